// Round 3
// baseline (289.774 us; speedup 1.0000x reference)
//
#include <hip/hip_runtime.h>
#include <hip/hip_bf16.h>

typedef _Float16 f16;
typedef f16 f16x8 __attribute__((ext_vector_type(8)));
typedef f16 f16x4 __attribute__((ext_vector_type(4)));
typedef float f32x4 __attribute__((ext_vector_type(4)));

#define QL 1024
#define KL 1024
#define DKD 64
#define NH 8
#define LNEPS 1e-5f

// ---- prep: K f32 -> f16 plane (same [bh][k][d] layout) ----
__global__ __launch_bounds__(256) void prep_kf(const float* __restrict__ K, f16* __restrict__ kf) {
  int i = (blockIdx.x * 256 + threadIdx.x) * 4;
  float4 v = *reinterpret_cast<const float4*>(K + i);
  f16x4 o;
  o[0] = (f16)v.x; o[1] = (f16)v.y; o[2] = (f16)v.z; o[3] = (f16)v.w;
  *reinterpret_cast<f16x4*>(kf + i) = o;
}

// ---- prep: V[bh][k][d] f32 -> vt[bh][d][k] f16 (transpose) ----
__global__ __launch_bounds__(256) void prep_vt(const float* __restrict__ V, f16* __restrict__ vt) {
  __shared__ float t[32][33];
  const int bh = blockIdx.z, k0 = blockIdx.x * 32, d0 = blockIdx.y * 32;
  const float* src = V + ((size_t)bh * KL + k0) * DKD + d0;
#pragma unroll
  for (int j = 0; j < 4; ++j) {
    int kk = threadIdx.y * 4 + j;
    t[kk][threadIdx.x] = src[kk * DKD + threadIdx.x];
  }
  __syncthreads();
  f16* dst = vt + ((size_t)bh * DKD + d0) * KL + k0;
#pragma unroll
  for (int j = 0; j < 4; ++j) {
    int dd = threadIdx.y * 4 + j;
    dst[dd * KL + threadIdx.x] = (f16)t[threadIdx.x][dd];
  }
}

// ---- pass 1: rowsum[bh][q] = sum_k exp(s); one head per block, 4 waves share K ----
__global__ __launch_bounds__(256) void stats_kernel(const float* __restrict__ Qm,
    const f16* __restrict__ kf, float* __restrict__ rowsum) {
  const int tid = threadIdx.x;
  const int lane = tid & 63, w = tid >> 6;
  const int m = lane & 15, g = lane >> 4;
  const int id = blockIdx.x;
  // XCD-local: xcd (id&7) owns batch (id&7); all 16 q-blocks of a bh on one XCD
  const int bh = (id & 7) * 8 + ((id >> 3) & 7);
  const int q0 = (id >> 6) * 64 + w * 16;

  f16x8 qf[2];
#pragma unroll
  for (int dc = 0; dc < 2; ++dc) {
    const float* qp = Qm + ((size_t)bh * QL + q0 + m) * DKD + dc * 32 + g * 8;
    float4 a = *reinterpret_cast<const float4*>(qp);
    float4 c = *reinterpret_cast<const float4*>(qp + 4);
    f16x8 q;
    q[0] = (f16)(a.x * 0.125f); q[1] = (f16)(a.y * 0.125f);
    q[2] = (f16)(a.z * 0.125f); q[3] = (f16)(a.w * 0.125f);
    q[4] = (f16)(c.x * 0.125f); q[5] = (f16)(c.y * 0.125f);
    q[6] = (f16)(c.z * 0.125f); q[7] = (f16)(c.w * 0.125f);
    qf[dc] = q;
  }
  float part[4] = {0.f, 0.f, 0.f, 0.f};
#pragma unroll 2
  for (int kt = 0; kt < 64; ++kt) {
    const f16* kb = kf + ((size_t)bh * KL + kt * 16 + m) * DKD + g * 8;
    f16x8 k0f = *reinterpret_cast<const f16x8*>(kb);
    f16x8 k1f = *reinterpret_cast<const f16x8*>(kb + 32);
    f32x4 acc = {0.f, 0.f, 0.f, 0.f};
    acc = __builtin_amdgcn_mfma_f32_16x16x32_f16(qf[0], k0f, acc, 0, 0, 0);
    acc = __builtin_amdgcn_mfma_f32_16x16x32_f16(qf[1], k1f, acc, 0, 0, 0);
#pragma unroll
    for (int ri = 0; ri < 4; ++ri) part[ri] += __expf(acc[ri]);
  }
#pragma unroll
  for (int ri = 0; ri < 4; ++ri) {
    float v = part[ri];
    v += __shfl_xor(v, 1); v += __shfl_xor(v, 2);
    v += __shfl_xor(v, 4); v += __shfl_xor(v, 8);
    part[ri] = v;
  }
  if (m == 0) {
#pragma unroll
    for (int ri = 0; ri < 4; ++ri) rowsum[(size_t)bh * QL + q0 + g * 4 + ri] = part[ri];
  }
}

// ---- pass 2 (split-k): S -> p -> mix -> LN -> att_map + partial PV ----
// block = (b, kc half of k, q16 tile); 4 waves; wave w owns S columns w*16+m
// within each k64 tile and heads {w, w+4} for PV.
__global__ __launch_bounds__(256, 4) void main_kernel(
    const float* __restrict__ Qm, const f16* __restrict__ kf, const f16* __restrict__ vt,
    const float* __restrict__ rowsum,
    const float* __restrict__ hA, const float* __restrict__ lnw, const float* __restrict__ lnb,
    float* __restrict__ outp, float* __restrict__ part1, float* __restrict__ att_map) {
  __shared__ __align__(16) f16 y_lds[2][NH][16][64];

  const int tid = threadIdx.x;
  const int lane = tid & 63, w = tid >> 6;
  const int m = lane & 15, g = lane >> 4;
  const int id = blockIdx.x;
  // XCD-local: batch b = id&7 lives entirely on XCD (id&7)
  const int b = id & 7, kc = (id >> 3) & 1, q0 = (id >> 4) * 16;

  float haR[64], wR[8], bR[8];
#pragma unroll
  for (int j = 0; j < 64; ++j) haR[j] = hA[j];
#pragma unroll
  for (int j = 0; j < 8; ++j) { wR[j] = lnw[j]; bR[j] = lnb[j]; }

  // Q fragments for all 8 heads, fp16, pre-scaled
  f16x8 qf[NH][2];
#pragma unroll
  for (int h = 0; h < NH; ++h)
#pragma unroll
    for (int dc = 0; dc < 2; ++dc) {
      const float* qp = Qm + (((size_t)(b * NH + h)) * QL + q0 + m) * DKD + dc * 32 + g * 8;
      float4 a = *reinterpret_cast<const float4*>(qp);
      float4 c = *reinterpret_cast<const float4*>(qp + 4);
      f16x8 q;
      q[0] = (f16)(a.x * 0.125f); q[1] = (f16)(a.y * 0.125f);
      q[2] = (f16)(a.z * 0.125f); q[3] = (f16)(a.w * 0.125f);
      q[4] = (f16)(c.x * 0.125f); q[5] = (f16)(c.y * 0.125f);
      q[6] = (f16)(c.z * 0.125f); q[7] = (f16)(c.w * 0.125f);
      qf[h][dc] = q;
    }
  // global rowsum (full-k normalizer)
  float inv_rs[NH][4];
#pragma unroll
  for (int h = 0; h < NH; ++h)
#pragma unroll
    for (int ri = 0; ri < 4; ++ri)
      inv_rs[h][ri] = 1.0f / rowsum[(size_t)(b * NH + h) * QL + q0 + g * 4 + ri];

  const size_t kbase_b = (size_t)b * NH * KL;
  f32x4 oacc[2][4];
#pragma unroll
  for (int hp = 0; hp < 2; ++hp)
#pragma unroll
    for (int dt = 0; dt < 4; ++dt) oacc[hp][dt] = (f32x4){0.f, 0.f, 0.f, 0.f};

  for (int kt = 0; kt < 8; ++kt) {
    const int kbase = kc * 512 + kt * 64;
    const int kcol = kbase + w * 16;
    const int buf = kt & 1;

    // S phase: 8 heads, columns kcol+m
    f32x4 pacc[NH];
    {
      const f16* kb = kf + (kbase_b + kcol + m) * DKD + g * 8;
#pragma unroll
      for (int h = 0; h < NH; ++h) {
        f16x8 k0f = *reinterpret_cast<const f16x8*>(kb + (size_t)h * KL * DKD);
        f16x8 k1f = *reinterpret_cast<const f16x8*>(kb + (size_t)h * KL * DKD + 32);
        f32x4 acc = {0.f, 0.f, 0.f, 0.f};
        acc = __builtin_amdgcn_mfma_f32_16x16x32_f16(qf[h][0], k0f, acc, 0, 0, 0);
        acc = __builtin_amdgcn_mfma_f32_16x16x32_f16(qf[h][1], k1f, acc, 0, 0, 0);
        pacc[h] = acc;
      }
    }
#pragma unroll
    for (int h = 0; h < NH; ++h)
#pragma unroll
      for (int ri = 0; ri < 4; ++ri)
        pacc[h][ri] = __expf(pacc[h][ri]) * inv_rs[h][ri];

    // mix + LN + att_map + y -> LDS (swizzled, verified round 2)
#pragma unroll
    for (int ri = 0; ri < 4; ++ri) {
      const int qq = g * 4 + ri;
      float mixed[8];
      float mu = 0.f;
#pragma unroll
      for (int hh = 0; hh < 8; ++hh) {
        float s = 0.f;
#pragma unroll
        for (int j = 0; j < 8; ++j) s = fmaf(pacc[j][ri], haR[j * 8 + hh], s);
        mixed[hh] = s; mu += s;
      }
      mu *= 0.125f;
      float var = 0.f;
#pragma unroll
      for (int hh = 0; hh < 8; ++hh) { float d = mixed[hh] - mu; var = fmaf(d, d, var); }
      var *= 0.125f;
      const float rsv = rsqrtf(var + LNEPS);
      float am = 0.f;
      const int kidx = ((((2 * w + (m >> 3)) ^ (qq & 7)) << 3) | (m & 7));
#pragma unroll
      for (int hh = 0; hh < 8; ++hh) {
        float y = (mixed[hh] - mu) * rsv * wR[hh] + bR[hh];
        am += y;
        y_lds[buf][hh][qq][kidx] = (f16)y;
      }
      att_map[((size_t)b * QL + q0 + qq) * KL + kcol + m] = am * 0.125f;
    }
    __syncthreads();  // y tile ready; dbuf covers WAR across iterations

    // PV phase: heads {w, w+4} over this k64
#pragma unroll
    for (int hp = 0; hp < 2; ++hp) {
      const int hh = w + hp * 4;
      const f16* vb = vt + (((size_t)(b * NH + hh)) * DKD + m) * KL + kbase + g * 8;
#pragma unroll
      for (int ks = 0; ks < 2; ++ks) {
        const f16x8 af = *reinterpret_cast<const f16x8*>(
            &y_lds[buf][hh][m][((ks * 4 + g) ^ (m & 7)) << 3]);
#pragma unroll
        for (int dt = 0; dt < 4; ++dt) {
          f16x8 vf = *reinterpret_cast<const f16x8*>(vb + (size_t)dt * 16 * KL + ks * 32);
          oacc[hp][dt] = __builtin_amdgcn_mfma_f32_16x16x32_f16(af, vf, oacc[hp][dt], 0, 0, 0);
        }
      }
    }
  }

  // epilogue: kc=0 -> outp, kc=1 -> partial (reduced later)
  float* dst = kc ? part1 : outp;
#pragma unroll
  for (int hp = 0; hp < 2; ++hp) {
    const int hh = w + hp * 4;
#pragma unroll
    for (int dt = 0; dt < 4; ++dt)
#pragma unroll
      for (int ri = 0; ri < 4; ++ri)
        dst[(((size_t)(b * NH + hh)) * QL + q0 + g * 4 + ri) * DKD + dt * 16 + m] =
            oacc[hp][dt][ri];
  }
}

// ---- out += partial ----
__global__ __launch_bounds__(256) void reduce_kernel(const float* __restrict__ p1,
                                                     float* __restrict__ outp) {
  size_t i = ((size_t)blockIdx.x * 256 + threadIdx.x) * 4;
  float4 a = *reinterpret_cast<const float4*>(outp + i);
  float4 c = *reinterpret_cast<const float4*>(p1 + i);
  a.x += c.x; a.y += c.y; a.z += c.z; a.w += c.w;
  *reinterpret_cast<float4*>(outp + i) = a;
}

extern "C" void kernel_launch(void* const* d_in, const int* in_sizes, int n_in,
                              void* d_out, int out_size, void* d_ws, size_t ws_size,
                              hipStream_t stream) {
  const float* Qm  = (const float*)d_in[0];
  const float* Km  = (const float*)d_in[1];
  const float* Vm  = (const float*)d_in[2];
  const float* hA  = (const float*)d_in[3];
  const float* lnw = (const float*)d_in[4];
  const float* lnb = (const float*)d_in[5];
  float* outp = (float*)d_out;
  float* att_map = outp + (size_t)64 * QL * DKD;

  char* ws = (char*)d_ws;
  f16* kfp   = (f16*)ws;                                   // 8 MB
  f16* vtp   = (f16*)(ws + (size_t)8388608);               // 8 MB
  float* rsm = (float*)(ws + (size_t)16777216);            // 256 KB
  float* p1  = (float*)(ws + (size_t)17039360);            // 16.8 MB

  prep_kf<<<4096, 256, 0, stream>>>(Km, kfp);
  prep_vt<<<dim3(32, 2, 64), dim3(32, 8), 0, stream>>>(Vm, vtp);
  stats_kernel<<<1024, 256, 0, stream>>>(Qm, kfp, rsm);
  main_kernel<<<1024, 256, 0, stream>>>(Qm, kfp, vtp, rsm, hA, lnw, lnb, outp, p1, att_map);
  reduce_kernel<<<4096, 256, 0, stream>>>(p1, outp);
}

// Round 4
// 240.769 us; speedup vs baseline: 1.2035x; 1.2035x over previous
//
#include <hip/hip_runtime.h>
#include <hip/hip_bf16.h>

typedef _Float16 f16;
typedef f16 f16x8 __attribute__((ext_vector_type(8)));
typedef f16 f16x4 __attribute__((ext_vector_type(4)));
typedef float f32x4 __attribute__((ext_vector_type(4)));

#define QL 1024
#define KL 1024
#define DKD 64
#define NH 8
#define LNEPS 1e-5f

// ---- prep: f32 -> f16 plane with scale (K: scale=1, Q: scale=1/8) ----
__global__ __launch_bounds__(256) void prep_cvt(const float* __restrict__ src,
                                                f16* __restrict__ dst, float scale) {
  int i = (blockIdx.x * 256 + threadIdx.x) * 4;
  float4 v = *reinterpret_cast<const float4*>(src + i);
  f16x4 o;
  o[0] = (f16)(v.x * scale); o[1] = (f16)(v.y * scale);
  o[2] = (f16)(v.z * scale); o[3] = (f16)(v.w * scale);
  *reinterpret_cast<f16x4*>(dst + i) = o;
}

// ---- prep: V[bh][k][d] f32 -> vt[bh][d][k] f16 (transpose) ----
__global__ __launch_bounds__(256) void prep_vt(const float* __restrict__ V, f16* __restrict__ vt) {
  __shared__ float t[32][33];
  const int bh = blockIdx.z, k0 = blockIdx.x * 32, d0 = blockIdx.y * 32;
  const float* src = V + ((size_t)bh * KL + k0) * DKD + d0;
#pragma unroll
  for (int j = 0; j < 4; ++j) {
    int kk = threadIdx.y * 4 + j;
    t[kk][threadIdx.x] = src[kk * DKD + threadIdx.x];
  }
  __syncthreads();
  f16* dst = vt + ((size_t)bh * DKD + d0) * KL + k0;
#pragma unroll
  for (int j = 0; j < 4; ++j) {
    int dd = threadIdx.y * 4 + j;
    dst[dd * KL + threadIdx.x] = (f16)t[threadIdx.x][dd];
  }
}

// ---- pass 1: rowsum[bh][q] = sum_k exp(s); one head per block, XCD-local K ----
__global__ __launch_bounds__(256) void stats_kernel(const f16* __restrict__ qf,
    const f16* __restrict__ kf, float* __restrict__ rowsum) {
  const int tid = threadIdx.x;
  const int lane = tid & 63, w = tid >> 6;
  const int m = lane & 15, g = lane >> 4;
  const int id = blockIdx.x;
  const int bh = (id & 7) * 8 + ((id >> 3) & 7);   // batch id&7 -> XCD id&7
  const int q0 = (id >> 6) * 64 + w * 16;

  f16x8 qv[2];
#pragma unroll
  for (int dc = 0; dc < 2; ++dc)
    qv[dc] = *reinterpret_cast<const f16x8*>(
        qf + ((size_t)bh * QL + q0 + m) * DKD + dc * 32 + g * 8);

  float part[4] = {0.f, 0.f, 0.f, 0.f};
#pragma unroll 2
  for (int kt = 0; kt < 64; ++kt) {
    const f16* kb = kf + ((size_t)bh * KL + kt * 16 + m) * DKD + g * 8;
    f16x8 k0f = *reinterpret_cast<const f16x8*>(kb);
    f16x8 k1f = *reinterpret_cast<const f16x8*>(kb + 32);
    f32x4 acc = {0.f, 0.f, 0.f, 0.f};
    acc = __builtin_amdgcn_mfma_f32_16x16x32_f16(qv[0], k0f, acc, 0, 0, 0);
    acc = __builtin_amdgcn_mfma_f32_16x16x32_f16(qv[1], k1f, acc, 0, 0, 0);
#pragma unroll
    for (int ri = 0; ri < 4; ++ri) part[ri] += __expf(acc[ri]);
  }
#pragma unroll
  for (int ri = 0; ri < 4; ++ri) {
    float v = part[ri];
    v += __shfl_xor(v, 1); v += __shfl_xor(v, 2);
    v += __shfl_xor(v, 4); v += __shfl_xor(v, 8);
    part[ri] = v;
  }
  if (m == 0) {
#pragma unroll
    for (int ri = 0; ri < 4; ++ri) rowsum[(size_t)bh * QL + q0 + g * 4 + ri] = part[ri];
  }
}

// ---- pass 2 (split-k): S -> p -> mix -> LN -> att_map + partial PV ----
// block = (b, kc, q16); 4 waves; wave w owns S columns w*16+m of each k64
// tile and heads {w, w+4} for PV. NO min-wave launch bound: body needs ~124
// VGPR (round 2 measured); forcing 4 w/EU spilled catastrophically (round 3).
__global__ __launch_bounds__(256) void main_kernel(
    const f16* __restrict__ qf, const f16* __restrict__ kf, const f16* __restrict__ vt,
    const float* __restrict__ rowsum,
    const float* __restrict__ hA, const float* __restrict__ lnw, const float* __restrict__ lnb,
    float* __restrict__ outp, float* __restrict__ part1, float* __restrict__ att_map) {
  __shared__ __align__(16) f16 y_lds[2][NH][16][64];

  const int tid = threadIdx.x;
  const int lane = tid & 63, w = tid >> 6;
  const int m = lane & 15, g = lane >> 4;
  const int id = blockIdx.x;
  const int b = id & 7, kc = (id >> 3) & 1, q0 = (id >> 4) * 16;  // batch b -> XCD b

  float haR[64], wR[8], bR[8];
#pragma unroll
  for (int j = 0; j < 64; ++j) haR[j] = hA[j];
#pragma unroll
  for (int j = 0; j < 8; ++j) { wR[j] = lnw[j]; bR[j] = lnb[j]; }

  // Q fragments for all 8 heads (pre-scaled f16 from prep)
  f16x8 qv[NH][2];
#pragma unroll
  for (int h = 0; h < NH; ++h)
#pragma unroll
    for (int dc = 0; dc < 2; ++dc)
      qv[h][dc] = *reinterpret_cast<const f16x8*>(
          qf + (((size_t)(b * NH + h)) * QL + q0 + m) * DKD + dc * 32 + g * 8);

  float inv_rs[NH][4];
#pragma unroll
  for (int h = 0; h < NH; ++h)
#pragma unroll
    for (int ri = 0; ri < 4; ++ri)
      inv_rs[h][ri] = 1.0f / rowsum[(size_t)(b * NH + h) * QL + q0 + g * 4 + ri];

  const size_t kbase_b = (size_t)b * NH * KL;
  f32x4 oacc[2][4];
#pragma unroll
  for (int hp = 0; hp < 2; ++hp)
#pragma unroll
    for (int dt = 0; dt < 4; ++dt) oacc[hp][dt] = (f32x4){0.f, 0.f, 0.f, 0.f};

  for (int kt = 0; kt < 8; ++kt) {
    const int kbase = kc * 512 + kt * 64;
    const int kcol = kbase + w * 16;
    const int buf = kt & 1;

    // S phase: 8 heads, columns kcol+m
    f32x4 pacc[NH];
    {
      const f16* kb = kf + (kbase_b + kcol + m) * DKD + g * 8;
#pragma unroll
      for (int h = 0; h < NH; ++h) {
        f16x8 k0f = *reinterpret_cast<const f16x8*>(kb + (size_t)h * KL * DKD);
        f16x8 k1f = *reinterpret_cast<const f16x8*>(kb + (size_t)h * KL * DKD + 32);
        f32x4 acc = {0.f, 0.f, 0.f, 0.f};
        acc = __builtin_amdgcn_mfma_f32_16x16x32_f16(qv[h][0], k0f, acc, 0, 0, 0);
        acc = __builtin_amdgcn_mfma_f32_16x16x32_f16(qv[h][1], k1f, acc, 0, 0, 0);
        pacc[h] = acc;
      }
    }
#pragma unroll
    for (int h = 0; h < NH; ++h)
#pragma unroll
      for (int ri = 0; ri < 4; ++ri)
        pacc[h][ri] = __expf(pacc[h][ri]) * inv_rs[h][ri];

    // mix + LN + att_map + y -> LDS (swizzled; verified 0 bank conflicts)
#pragma unroll
    for (int ri = 0; ri < 4; ++ri) {
      const int qq = g * 4 + ri;
      float mixed[8];
      float mu = 0.f;
#pragma unroll
      for (int hh = 0; hh < 8; ++hh) {
        float s = 0.f;
#pragma unroll
        for (int j = 0; j < 8; ++j) s = fmaf(pacc[j][ri], haR[j * 8 + hh], s);
        mixed[hh] = s; mu += s;
      }
      mu *= 0.125f;
      float var = 0.f;
#pragma unroll
      for (int hh = 0; hh < 8; ++hh) { float d = mixed[hh] - mu; var = fmaf(d, d, var); }
      var *= 0.125f;
      const float rsv = rsqrtf(var + LNEPS);
      float am = 0.f;
      const int kidx = ((((2 * w + (m >> 3)) ^ (qq & 7)) << 3) | (m & 7));
#pragma unroll
      for (int hh = 0; hh < 8; ++hh) {
        float y = (mixed[hh] - mu) * rsv * wR[hh] + bR[hh];
        am += y;
        y_lds[buf][hh][qq][kidx] = (f16)y;
      }
      att_map[((size_t)b * QL + q0 + qq) * KL + kcol + m] = am * 0.125f;
    }
    __syncthreads();  // y tile ready; dbuf covers WAR across iterations

    // PV phase: heads {w, w+4} over this k64
#pragma unroll
    for (int hp = 0; hp < 2; ++hp) {
      const int hh = w + hp * 4;
      const f16* vb = vt + (((size_t)(b * NH + hh)) * DKD + m) * KL + kbase + g * 8;
#pragma unroll
      for (int ks = 0; ks < 2; ++ks) {
        const f16x8 af = *reinterpret_cast<const f16x8*>(
            &y_lds[buf][hh][m][((ks * 4 + g) ^ (m & 7)) << 3]);
#pragma unroll
        for (int dt = 0; dt < 4; ++dt) {
          f16x8 vf = *reinterpret_cast<const f16x8*>(vb + (size_t)dt * 16 * KL + ks * 32);
          oacc[hp][dt] = __builtin_amdgcn_mfma_f32_16x16x32_f16(af, vf, oacc[hp][dt], 0, 0, 0);
        }
      }
    }
  }

  // epilogue: kc=0 -> outp, kc=1 -> partial (reduced later)
  float* dst = kc ? part1 : outp;
#pragma unroll
  for (int hp = 0; hp < 2; ++hp) {
    const int hh = w + hp * 4;
#pragma unroll
    for (int dt = 0; dt < 4; ++dt)
#pragma unroll
      for (int ri = 0; ri < 4; ++ri)
        dst[(((size_t)(b * NH + hh)) * QL + q0 + g * 4 + ri) * DKD + dt * 16 + m] =
            oacc[hp][dt][ri];
  }
}

// ---- out += partial ----
__global__ __launch_bounds__(256) void reduce_kernel(const float* __restrict__ p1,
                                                     float* __restrict__ outp) {
  size_t i = ((size_t)blockIdx.x * 256 + threadIdx.x) * 4;
  float4 a = *reinterpret_cast<const float4*>(outp + i);
  float4 c = *reinterpret_cast<const float4*>(p1 + i);
  a.x += c.x; a.y += c.y; a.z += c.z; a.w += c.w;
  *reinterpret_cast<float4*>(outp + i) = a;
}

extern "C" void kernel_launch(void* const* d_in, const int* in_sizes, int n_in,
                              void* d_out, int out_size, void* d_ws, size_t ws_size,
                              hipStream_t stream) {
  const float* Qm  = (const float*)d_in[0];
  const float* Km  = (const float*)d_in[1];
  const float* Vm  = (const float*)d_in[2];
  const float* hA  = (const float*)d_in[3];
  const float* lnw = (const float*)d_in[4];
  const float* lnb = (const float*)d_in[5];
  float* outp = (float*)d_out;
  float* att_map = outp + (size_t)64 * QL * DKD;

  char* ws = (char*)d_ws;
  f16* kfp   = (f16*)ws;                                   // 8 MB
  f16* vtp   = (f16*)(ws + (size_t)8388608);               // 8 MB
  f16* qfp   = (f16*)(ws + (size_t)16777216);              // 8 MB
  float* rsm = (float*)(ws + (size_t)25165824);            // 256 KB
  float* p1  = (float*)(ws + (size_t)25427968);            // 16.8 MB

  prep_cvt<<<4096, 256, 0, stream>>>(Km, kfp, 1.0f);
  prep_cvt<<<4096, 256, 0, stream>>>(Qm, qfp, 0.125f);
  prep_vt<<<dim3(32, 2, 64), dim3(32, 8), 0, stream>>>(Vm, vtp);
  stats_kernel<<<1024, 256, 0, stream>>>(qfp, kfp, rsm);
  main_kernel<<<1024, 256, 0, stream>>>(qfp, kfp, vtp, rsm, hA, lnw, lnb, outp, p1, att_map);
  reduce_kernel<<<4096, 256, 0, stream>>>(p1, outp);
}